// Round 13
// baseline (174.310 us; speedup 1.0000x reference)
//
#include <hip/hip_runtime.h>
#include <hip/hip_cooperative_groups.h>
#include <math.h>

namespace cg = cooperative_groups;

typedef __bf16 bf16;
typedef __bf16 bf16x2 __attribute__((ext_vector_type(2)));
typedef __bf16 bf16x4 __attribute__((ext_vector_type(4)));
typedef __bf16 bf16x8 __attribute__((ext_vector_type(8)));
typedef float  f32x4  __attribute__((ext_vector_type(4)));

#define BZd 16
#define INd 512
#define Sd  512
#define Od  512
#define Ld  2048
#define CLd 128
#define NCd (Ld / CLd)   // 16 chunks of 128

__device__ __forceinline__ int keyf(int r) { return (r & 3) ^ ((r >> 2) & 3); }

// ============ fused front: prep + transpose + gemm_bu(+ce) + L2-local scan ============
// Cooperative, grid 256 x 512. Phase0: conv B/C/D (+dfa), A_diag, u->ut transpose.
// Phase1: 256x256 bf16 MFMA GEMM (vmcnt(4) pipeline) producing bu + chunk-end ce.
// Phase2: each block scans in-place the xs rows/cols IT wrote (L2-warm), carry from ce.
__global__ __launch_bounds__(512, 2) void fused_front(
    const float* __restrict__ u, const float* __restrict__ Au,
    const float* __restrict__ Bm, const float* __restrict__ Cm,
    const float* __restrict__ Dm, const float* __restrict__ h0,
    bf16* __restrict__ ut, bf16* __restrict__ Bb, bf16* __restrict__ Cb,
    bf16* __restrict__ Db, float* __restrict__ A_diag, int* __restrict__ dfa,
    float* __restrict__ ce, bf16* __restrict__ xs)
{
    constexpr int RS = 32, ASZ = 256 * RS, SLOT = ASZ + 256 * 32;
    __shared__ bf16 lds[4 * SLOT];      // 128 KiB, reused across phases
    __shared__ int sred[8];

    const int tid = threadIdx.x, bid = blockIdx.x;
    cg::grid_group gridg = cg::this_grid();

    // ---------------- phase 0: weight conv + A_diag + dfa + transpose ----------------
    if (bid < 128) {
        int unit = bid * 512 + tid;                 // 65536 f32x4 units per matrix
        {
            f32x4 v = *(const f32x4*)&Bm[(size_t)unit * 4];
            bf16x4 o = { (bf16)v[0], (bf16)v[1], (bf16)v[2], (bf16)v[3] };
            *(bf16x4*)&Bb[(size_t)unit * 4] = o;
        }
        f32x4 v = *(const f32x4*)&Dm[(size_t)unit * 4];
        bf16x4 o = { (bf16)v[0], (bf16)v[1], (bf16)v[2], (bf16)v[3] };
        *(bf16x4*)&Db[(size_t)unit * 4] = o;
        int nz = (v[0] != 0.f) | (v[1] != 0.f) | (v[2] != 0.f) | (v[3] != 0.f);
        unsigned long long bl = __ballot(nz);
        if ((tid & 63) == 0) sred[tid >> 6] = (bl != 0ull);
        __syncthreads();
        if (tid == 0)
            dfa[bid] = sred[0] | sred[1] | sred[2] | sred[3] |
                       sred[4] | sred[5] | sred[6] | sred[7];
    } else {
        int unit = (bid - 128) * 512 + tid;
        f32x4 v = *(const f32x4*)&Cm[(size_t)unit * 4];
        bf16x4 o = { (bf16)v[0], (bf16)v[1], (bf16)v[2], (bf16)v[3] };
        *(bf16x4*)&Cb[(size_t)unit * 4] = o;
        if (tid == 0) dfa[bid] = 0;
        if (bid == 255) {
            float x = Au[tid];
            A_diag[tid] = -(fmaxf(x, 0.0f) + log1pf(expf(-fabsf(x))));
        }
    }
    __syncthreads();

    // transpose: 4096 tiles of 64x64; block handles 16, two per pass (512 threads)
    {
        bf16* tb = lds + (tid >> 8) * (64 * 73);    // two padded 64x73 buffers
        int stid = tid & 255;
        int tx = stid & 15, ty = stid >> 4;
        #pragma unroll 1
        for (int it = 0; it < 8; ++it) {
            int T = bid * 16 + it * 2 + (tid >> 8);
            int b = T >> 8, rem = T & 255;
            int i0 = (rem >> 5) * 64, l0 = (rem & 31) * 64;
            const float* ub = u + ((size_t)b * INd + i0) * Ld + l0;
            __syncthreads();
            #pragma unroll
            for (int r = 0; r < 4; ++r) {
                int il = r * 16 + ty;
                f32x4 v = *(const f32x4*)&ub[(size_t)il * Ld + tx * 4];
                tb[il * 73 + tx * 4 + 0] = (bf16)v[0];
                tb[il * 73 + tx * 4 + 1] = (bf16)v[1];
                tb[il * 73 + tx * 4 + 2] = (bf16)v[2];
                tb[il * 73 + tx * 4 + 3] = (bf16)v[3];
            }
            __syncthreads();
            bf16* uo = ut + ((size_t)b * Ld + l0) * INd + i0;
            #pragma unroll
            for (int q2 = 0; q2 < 2; ++q2) {
                int q = q2 * 256 + stid;
                int lr = q >> 3;
                int ic = (q & 7) * 8;
                bf16x8 o;
                #pragma unroll
                for (int e = 0; e < 8; ++e) o[e] = tb[(ic + e) * 73 + lr];
                *(bf16x8*)&uo[(size_t)lr * INd + ic] = o;
            }
        }
    }

    gridg.sync();

    // ---------------- phase 1: gemm_bu 256x256 (vmcnt(4) pipeline) + ce ----------------
    const int lane = tid & 63, w = tid >> 6;
    int cpx = 256 >> 3;
    int swz = (bid & 7) * cpx + (bid >> 3);
    int b  = swz / 16;                  // NX*NY = 2*8
    int r0 = swz - b * 16;
    int by = r0 >> 1;                   // 0..7  l-tile
    int bx = r0 & 1;                    // 0..1  s-tile

    const int wm = w >> 2, wn = w & 3;
    const int fr = lane & 15, g = lane >> 4;

    {
        const bf16* Ab = ut + (size_t)b * Ld * INd + (size_t)(by * 256) * 512;
        const bf16* Bp = Bb + (size_t)(bx * 256) * 512;

        f32x4 acc[8][4];
        #pragma unroll
        for (int i = 0; i < 8; ++i)
            #pragma unroll
            for (int j = 0; j < 4; ++j)
                acc[i][j] = (f32x4){0.f, 0.f, 0.f, 0.f};

        #define GLD16(srcP, dstElem) __builtin_amdgcn_global_load_lds( \
            (const __attribute__((address_space(1))) void*)(srcP), \
            (__attribute__((address_space(3))) void*)&lds[dstElem], 16, 0, 0)

        auto gldA = [&](int U) {
            #pragma unroll
            for (int rb = 0; rb < 2; ++rb) {
                int row = rb * 128 + (tid >> 2);
                int cs = (tid & 3) ^ keyf(row);
                GLD16(Ab + (size_t)row * 512 + U * 32 + cs * 8,
                      (U & 3) * SLOT + (rb * 128 + w * 16) * 32);
            }
        };
        auto gldB = [&](int U) {
            #pragma unroll
            for (int rb = 0; rb < 2; ++rb) {
                int row = rb * 128 + (tid >> 2);
                int cs = (tid & 3) ^ keyf(row);
                GLD16(Bp + (size_t)row * 512 + U * 32 + cs * 8,
                      (U & 3) * SLOT + ASZ + (rb * 128 + w * 16) * 32);
            }
        };

        gldA(0); gldB(0); gldA(1); gldB(1);

        for (int U = 0; U < 16; ++U) {
            if (U < 15) { asm volatile("s_waitcnt vmcnt(4)" ::: "memory"); }
            else        { asm volatile("s_waitcnt vmcnt(0)" ::: "memory"); }
            __builtin_amdgcn_sched_barrier(0);
            __builtin_amdgcn_s_barrier();
            __builtin_amdgcn_sched_barrier(0);
            bf16x8 av[8], bv[4];
            {
                const bf16* As = &lds[(U & 3) * SLOT];
                const bf16* Bs = &lds[(U & 3) * SLOT + ASZ];
                #pragma unroll
                for (int i = 0; i < 8; ++i) {
                    int R = wm * 128 + i * 16 + fr;
                    av[i] = *(const bf16x8*)&As[R * RS + (g ^ keyf(R)) * 8];
                }
                #pragma unroll
                for (int j = 0; j < 4; ++j) {
                    int R = wn * 64 + j * 16 + fr;
                    bv[j] = *(const bf16x8*)&Bs[R * 32 + (g ^ keyf(R)) * 8];
                }
            }
            if (U + 2 < 16) gldA(U + 2);
            if (U + 2 < 16) gldB(U + 2);
            __builtin_amdgcn_s_setprio(1);
            #pragma unroll
            for (int i = 0; i < 8; ++i)
                #pragma unroll
                for (int j = 0; j < 4; ++j)
                    acc[i][j] = __builtin_amdgcn_mfma_f32_16x16x32_bf16(av[i], bv[j], acc[i][j], 0, 0, 0);
            __builtin_amdgcn_s_setprio(0);
        }
        #undef GLD16

        int n0 = bx * 256 + wn * 64 + fr;
        int m0 = by * 256 + wm * 128 + g * 4;

        // fused chunk-end scan: wave rows wm*128..+128 == chunk by*2+wm
        #pragma unroll
        for (int j = 0; j < 4; ++j) {
            float a = A_diag[n0 + j * 16];
            float a2 = a * a, a4 = a2 * a2, a8 = a4 * a4, a16 = a8 * a8;
            float S = 0.f;
            #pragma unroll
            for (int i = 0; i < 8; ++i) {
                f32x4 v = acc[i][j];
                float e = fmaf(fmaf(fmaf(v[0], a, v[1]), a, v[2]), a, v[3]);
                float e0 = __shfl(e, fr), e1 = __shfl(e, fr + 16);
                float e2 = __shfl(e, fr + 32), e3 = __shfl(e, fr + 48);
                float E = fmaf(fmaf(fmaf(e0, a4, e1), a4, e2), a4, e3);
                S = fmaf(S, a16, E);
            }
            if (g == 0)
                ce[((size_t)b * NCd + (by * 2 + wm)) * Sd + n0 + j * 16] = S;
        }

        // store raw bu (bf16): C/D layout col=lane&15, row=(lane>>4)*4+reg
        bf16* out = xs + (size_t)b * Ld * Sd;
        #pragma unroll
        for (int i = 0; i < 8; ++i)
            #pragma unroll
            for (int j = 0; j < 4; ++j)
                #pragma unroll
                for (int q = 0; q < 4; ++q)
                    out[(size_t)(m0 + i * 16 + q) * Sd + n0 + j * 16] = (bf16)acc[i][j][q];
    }

    gridg.sync();

    // ---------------- phase 2: L2-local scan of this block's own xs region ----------------
    // 256 chains: c in {2by, 2by+1}, s-pair in [bx*128, +128)
    if (tid < 256) {
        int c  = by * 2 + (tid >> 7);
        int sp = bx * 128 + (tid & 127);
        int s  = sp * 2;
        float a0 = A_diag[s], a1 = A_diag[s + 1];
        float acl0 = a0, acl1 = a1;
        #pragma unroll
        for (int i = 0; i < 7; ++i) { acl0 *= acl0; acl1 *= acl1; }   // a^128
        float x0 = h0[s], x1 = h0[s + 1];
        for (int cp = 0; cp < c; ++cp) {
            float2 e = *(const float2*)&ce[((size_t)b * NCd + cp) * Sd + s];
            x0 = fmaf(acl0, x0, e.x);
            x1 = fmaf(acl1, x1, e.y);
        }
        bf16* p = xs + ((size_t)b * Ld + (size_t)c * CLd) * Sd + s;
        #pragma unroll 4
        for (int j = 0; j < CLd; ++j) {
            bf16x2 v = *(const bf16x2*)&p[(size_t)j * Sd];
            x0 = fmaf(a0, x0, (float)v[0]);
            x1 = fmaf(a1, x1, (float)v[1]);
            bf16x2 o = { (bf16)x0, (bf16)x1 };
            *(bf16x2*)&p[(size_t)j * Sd] = o;
        }
    }
}

// ============ gemm_y: 256x256, A=C, B=xs, cold D*u pass iff D!=0 (proven) ============
__global__ __launch_bounds__(512, 2) void gemm_y256(
    const bf16* __restrict__ Cb,
    const float* __restrict__ Uf,
    const bf16* __restrict__ xs,
    const bf16* __restrict__ Dbf,
    const int* __restrict__ dfa,
    float* __restrict__ Y)
{
    constexpr int RS = 32, ASZ = 256 * RS, SLOT = ASZ + 256 * 32;
    __shared__ bf16 lds[4 * SLOT];

    const int tid = threadIdx.x;
    const int lane = tid & 63, w = tid >> 6;

    int nwg = gridDim.x, bid = blockIdx.x;
    int cpx = nwg >> 3;
    int swz = (bid & 7) * cpx + (bid >> 3);
    int b  = swz / 16;                  // NX*NY = 8*2
    int r0 = swz - b * 16;
    int by = r0 >> 3;                   // 0..1  o-tile
    int bx = r0 & 7;                    // 0..7  l-tile

    const int wm = w >> 2, wn = w & 3;
    const int fr = lane & 15, g = lane >> 4;
    const int iq = tid & 7, lq = tid >> 3;

    const bf16*  Ab = Cb + (size_t)(by * 256) * 512;
    const float* Ub = Uf + (size_t)b * INd * Ld;
    const bf16*  Bp = xs + (size_t)b * Ld * Sd + (size_t)(bx * 256) * 512;

    int extra;
    {
        int4 f = ((const int4*)dfa)[lane];
        extra = __any((f.x | f.y | f.z | f.w) != 0) ? 1 : 0;
    }

    f32x4 acc[8][4];
    #pragma unroll
    for (int i = 0; i < 8; ++i)
        #pragma unroll
        for (int j = 0; j < 4; ++j)
            acc[i][j] = (f32x4){0.f, 0.f, 0.f, 0.f};

    #define GLD16(srcP, dstElem) __builtin_amdgcn_global_load_lds( \
        (const __attribute__((address_space(1))) void*)(srcP), \
        (__attribute__((address_space(3))) void*)&lds[dstElem], 16, 0, 0)

    auto gldA = [&](int U) {
        #pragma unroll
        for (int rb = 0; rb < 2; ++rb) {
            int row = rb * 128 + (tid >> 2);
            int cs = (tid & 3) ^ keyf(row);
            GLD16(Ab + (size_t)row * 512 + U * 32 + cs * 8,
                  (U & 3) * SLOT + (rb * 128 + w * 16) * 32);
        }
    };
    auto gldB = [&](int U) {
        #pragma unroll
        for (int rb = 0; rb < 2; ++rb) {
            int row = rb * 128 + (tid >> 2);
            int cs = (tid & 3) ^ keyf(row);
            GLD16(Bp + (size_t)row * 512 + U * 32 + cs * 8,
                  (U & 3) * SLOT + ASZ + (rb * 128 + w * 16) * 32);
        }
    };
    auto readFrags = [&](int slot, bf16x8* avf, bf16x8* bvf) {
        const bf16* As = &lds[slot * SLOT];
        const bf16* Bs = &lds[slot * SLOT + ASZ];
        #pragma unroll
        for (int i = 0; i < 8; ++i) {
            int R = wm * 128 + i * 16 + fr;
            avf[i] = *(const bf16x8*)&As[R * RS + (g ^ keyf(R)) * 8];
        }
        #pragma unroll
        for (int j = 0; j < 4; ++j) {
            int R = wn * 64 + j * 16 + fr;
            bvf[j] = *(const bf16x8*)&Bs[R * 32 + (g ^ keyf(R)) * 8];
        }
    };

    gldA(0); gldB(0); gldA(1); gldB(1);

    for (int U = 0; U < 16; ++U) {
        if (U < 15) { asm volatile("s_waitcnt vmcnt(4)" ::: "memory"); }
        else        { asm volatile("s_waitcnt vmcnt(0)" ::: "memory"); }
        __builtin_amdgcn_sched_barrier(0);
        __builtin_amdgcn_s_barrier();
        __builtin_amdgcn_sched_barrier(0);
        bf16x8 av[8], bv[4];
        readFrags(U & 3, av, bv);
        if (U + 2 < 16) gldA(U + 2);
        if (U + 2 < 16) gldB(U + 2);
        __builtin_amdgcn_s_setprio(1);
        #pragma unroll
        for (int i = 0; i < 8; ++i)
            #pragma unroll
            for (int j = 0; j < 4; ++j)
                acc[i][j] = __builtin_amdgcn_mfma_f32_16x16x32_bf16(av[i], bv[j], acc[i][j], 0, 0, 0);
        __builtin_amdgcn_s_setprio(0);
    }

    // cold pass (D != 0 only; correctness path)
    if (extra) {
        #pragma unroll 1
        for (int T = 0; T < 16; ++T) {
            int k0 = T * 32;
            __builtin_amdgcn_s_barrier();
            f32x4 r4[4];
            #pragma unroll
            for (int d = 0; d < 4; ++d)
                r4[d] = *(const f32x4*)&Ub[(size_t)(k0 + iq * 4 + d) * Ld + bx * 256 + lq * 4];
            #pragma unroll
            for (int rb = 0; rb < 2; ++rb) {
                int row = rb * 128 + (tid >> 2);
                int cs = (tid & 3) ^ keyf(row);
                GLD16(Dbf + (size_t)(by * 256 + row) * 512 + k0 + cs * 8,
                      (rb * 128 + w * 16) * 32);
            }
            asm volatile("s_waitcnt vmcnt(0)" ::: "memory");
            #pragma unroll
            for (int dl = 0; dl < 4; ++dl) {
                int r = lq * 4 + dl;
                bf16x4 wv = { (bf16)r4[0][dl], (bf16)r4[1][dl], (bf16)r4[2][dl], (bf16)r4[3][dl] };
                int e = ((iq >> 1) ^ keyf(r)) * 8 + (iq & 1) * 4;
                *(bf16x4*)&lds[ASZ + r * 32 + e] = wv;
            }
            asm volatile("s_waitcnt lgkmcnt(0)" ::: "memory");
            __builtin_amdgcn_s_barrier();
            bf16x8 av[8], bv[4];
            readFrags(0, av, bv);
            #pragma unroll
            for (int i = 0; i < 8; ++i)
                #pragma unroll
                for (int j = 0; j < 4; ++j)
                    acc[i][j] = __builtin_amdgcn_mfma_f32_16x16x32_bf16(av[i], bv[j], acc[i][j], 0, 0, 0);
        }
    }
    #undef GLD16

    int n0 = bx * 256 + wn * 64 + fr;
    int m0 = by * 256 + wm * 128 + g * 4;
    float* out = Y + (size_t)b * Od * Ld;
    #pragma unroll
    for (int i = 0; i < 8; ++i)
        #pragma unroll
        for (int j = 0; j < 4; ++j)
            #pragma unroll
            for (int q = 0; q < 4; ++q)
                out[(size_t)(m0 + i * 16 + q) * Ld + n0 + j * 16] = acc[i][j][q];
}

extern "C" void kernel_launch(void* const* d_in, const int* in_sizes, int n_in,
                              void* d_out, int out_size, void* d_ws, size_t ws_size,
                              hipStream_t stream) {
    const float* u  = (const float*)d_in[0];
    const float* Au = (const float*)d_in[1];
    const float* Bm = (const float*)d_in[2];
    const float* Cm = (const float*)d_in[3];
    const float* Dm = (const float*)d_in[4];
    const float* h0 = (const float*)d_in[5];
    float* Y = (float*)d_out;

    char* ws = (char*)d_ws;
    bf16* xs = (bf16*)ws;                              // 32 MiB: bu -> scanned xs (bf16)
    bf16* ut = (bf16*)(ws + (32ull << 20));            // 32 MiB
    bf16* Bb = (bf16*)(ws + (64ull << 20));            // 512 KiB each
    bf16* Cb = Bb + 262144;
    bf16* Db = Cb + 262144;
    float* A_diag = (float*)(ws + (64ull << 20) + 3ull * 524288);   // 2 KiB
    float* ce     = A_diag + 512;                      // 512 KiB
    int*   dfa    = (int*)(ce + (size_t)BZd * NCd * Sd);  // 256 ints, written every call

    void* args[] = { (void*)&u, (void*)&Au, (void*)&Bm, (void*)&Cm, (void*)&Dm,
                     (void*)&h0, (void*)&ut, (void*)&Bb, (void*)&Cb, (void*)&Db,
                     (void*)&A_diag, (void*)&dfa, (void*)&ce, (void*)&xs };
    hipLaunchCooperativeKernel((const void*)fused_front, dim3(256), dim3(512),
                               args, 0, stream);

    gemm_y256<<<256, 512, 0, stream>>>(Cb, u, xs, Db, dfa, Y);
}